// Round 17
// baseline (318.579 us; speedup 1.0000x reference)
//
#include <hip/hip_runtime.h>
#include <hip/hip_fp16.h>

#define NN 8192
#define DD 128

typedef _Float16 f16x8 __attribute__((ext_vector_type(8)));
typedef _Float16 f16x4 __attribute__((ext_vector_type(4)));
typedef float f32x4 __attribute__((ext_vector_type(4)));

// ---------------------------------------------------------------------------
// prep: Xc[row][0..127] = f16(x), Xc[row][128..255] = f16(x - f16(x)).
// sim = Xc @ Xc^T equals x@x^T up to ~1e-6.
// ---------------------------------------------------------------------------
__global__ __launch_bounds__(256) void prep_kernel(const float* __restrict__ X,
                                                   _Float16* __restrict__ Xc) {
  const int t = blockIdx.x * 256 + threadIdx.x;  // 8 elems per thread
  const size_t base = (size_t)t * 8;
  const int row = (int)(base >> 7);
  const int col = (int)(base & 127);
  float4 a = *(const float4*)&X[base];
  float4 b = *(const float4*)&X[base + 4];
  const float av[8] = {a.x, a.y, a.z, a.w, b.x, b.y, b.z, b.w};
  f16x8 h, l;
#pragma unroll
  for (int e = 0; e < 8; ++e) {
    const _Float16 hh = (_Float16)av[e];
    h[e] = hh;
    l[e] = (_Float16)(av[e] - (float)hh);
  }
  *(f16x8*)&Xc[(size_t)row * 256 + col] = h;
  *(f16x8*)&Xc[(size_t)row * 256 + 128 + col] = l;
}

// ---------------------------------------------------------------------------
// sim = Xc @ Xc^T (R16 structure, f16 in-place sim). ONE CHANGE (R17):
// __launch_bounds__(512,6) -> 3 blocks/CU (144 KB of 160 KB LDS), up from 2.
// More resident blocks mask each block's per-K-step vmcnt(0)+barrier drain.
// VGPR check: cap 2048/6=341 >> ~150 live regs -> no R11-style spill.
// sim stored as F16 IN-PLACE: sim row i (16 KB) = first half of grad row i;
// row_kernel block i reads exactly what it later overwrites -> hazard-free.
// Geometry: 256x128 tile, 512 thr (8 waves 4x2), wave tile 64x64, BK=32,
// 8 K-steps, double-buffered 24KB buffers = 48 KB LDS.
// SYMMETRY ABANDONED (R2,R13). L3 games abandoned (R14,R15).
// DETERMINISM RULE (R9): plain __syncthreads() only.
// Schedule: STAGE(0); sync; { STAGE(ks+1); compute(ks); sync; }
// Swizzle: chunk ^= row&3 on BOTH global source (inverse) and ds_read.
// A/B fragments share the identical k-mapping -> k-permutation cancels.
// C/D layout (m89): col=lane&15, row=(lane>>4)*4+reg.
// Epilogue: TrH 64x136 f16, 4 phases, f16x8 stores. Regular (non-NT) stores:
// simF16 lines stay L3-resident for row_kernel and are overwritten by its NT
// grad stores before writeback -> most never reach HBM.
// ---------------------------------------------------------------------------
__global__ __launch_bounds__(512, 6) void sim_mfma_kernel(
    const _Float16* __restrict__ Xc, char* __restrict__ simBytes) {
  __shared__ char smem[49152];  // buf b @ b*24576 (A 16KB, B 8KB); TrH unions

  // bijective XCD swizzle (2048 % 8 == 0)
  const int flat = blockIdx.x;
  const int swz = (flat & 7) * 256 + (flat >> 3);
  const int i0 = (swz >> 6) << 8;  // tile row (32 row-tiles of 256)
  const int j0 = (swz & 63) << 7;  // tile col (64 col-tiles of 128)

  const int tid = threadIdx.x;
  const int lane = tid & 63;
  const int w = tid >> 6;
  const int m = lane & 15, kq = lane >> 4;
  const int wr = w >> 1, wc = w & 1;  // wave rows wr*64+.., cols wc*64+..

  // Staging coords: 3 chunks of 16B per thread per K-step (A 16KB + B 8KB).
  int sg_off[3], sd_off[3], sg_row[3];
#pragma unroll
  for (int it = 0; it < 3; ++it) {
    const int C = it * 512 + tid;
    const int rq = C >> 2;          // row-quad index
    const int k4 = C & 3;
    const int k4p = k4 ^ (rq & 3);  // inverse swizzle on global source
    sg_row[it] = (C < 1024) ? (i0 + rq) : (j0 + rq - 256);
    sg_off[it] = k4p << 4;
    sd_off[it] = C * 16;
  }

#define STAGE(ks, b)                                                         \
  {                                                                          \
    _Pragma("unroll") for (int it = 0; it < 3; ++it) {                       \
      const char* g = (const char*)Xc + ((size_t)sg_row[it] << 9) +          \
                      (ks)*64 + sg_off[it];                                  \
      __builtin_amdgcn_global_load_lds(                                      \
          (const __attribute__((address_space(1))) void*)g,                  \
          (__attribute__((address_space(3))) void*)(smem + (b)*24576 +       \
                                                    sd_off[it]),             \
          16, 0, 0);                                                         \
    }                                                                        \
  }

  f32x4 acc[4][4] = {};

  STAGE(0, 0);
  __syncthreads();  // stage(0) landed (vmcnt 0 + barrier)

#pragma unroll
  for (int ks = 0; ks < 8; ++ks) {
    const int b = ks & 1;
    if (ks < 7) STAGE(ks + 1, b ^ 1);  // prefetch; drained at step-end sync
    const _Float16* As = (const _Float16*)(smem + b * 24576);
    const _Float16* Bs = (const _Float16*)(smem + b * 24576 + 16384);
    f16x8 af[4], bf[4];
#pragma unroll
    for (int f = 0; f < 4; ++f) {
      const int R = wr * 64 + f * 16 + m;  // R&3 == m&3
      af[f] = *(const f16x8*)(As + R * 32 + ((kq ^ (R & 3)) << 3));
    }
#pragma unroll
    for (int g = 0; g < 4; ++g) {
      const int R = wc * 64 + g * 16 + m;
      bf[g] = *(const f16x8*)(Bs + R * 32 + ((kq ^ (R & 3)) << 3));
    }
#pragma unroll
    for (int f = 0; f < 4; ++f)
#pragma unroll
      for (int g = 0; g < 4; ++g)
        acc[f][g] = __builtin_amdgcn_mfma_f32_16x16x32_f16(af[f], bf[g],
                                                           acc[f][g], 0, 0, 0);
    __syncthreads();  // drains vmcnt+lgkm; next-step buffer ready, WAR safe
  }
#undef STAGE

  // Epilogue: 4 phases of 64 rows through LDS as f16; TrH = 64 x 136 f16.
  _Float16* TrH = (_Float16*)smem;
#pragma unroll
  for (int ph = 0; ph < 4; ++ph) {
    if (ph) __syncthreads();
    if (wr == ph) {  // 2 waves (wc=0,1) own this 64-row band
#pragma unroll
      for (int f = 0; f < 4; ++f)
#pragma unroll
        for (int g = 0; g < 4; ++g)
#pragma unroll
          for (int rg = 0; rg < 4; ++rg)
            TrH[(f * 16 + kq * 4 + rg) * 136 + wc * 64 + g * 16 + m] =
                (_Float16)acc[f][g][rg];
    }
    __syncthreads();
#pragma unroll
    for (int it = 0; it < 2; ++it) {
      const int F = it * 512 + tid;   // [0,1024): 64 rows x 16 chunks
      const int row = F >> 4;
      const int c16 = F & 15;
      const f16x8 v = *(const f16x8*)&TrH[row * 136 + c16 * 8];
      char* dst = simBytes + (size_t)(i0 + ph * 64 + row) * 32768 +
                  (size_t)j0 * 2 + c16 * 16;
      *(f16x8*)dst = v;
    }
  }
}

// ---------------------------------------------------------------------------
// row_kernel: one block per row; sim row read as f16 from the first half of
// this block's own grad row (in-place), converted to f32 in registers.
// Native transcendentals, branchless epilogue, non-temporal output stores.
// ---------------------------------------------------------------------------
__global__ __launch_bounds__(256) void row_kernel(const char* simBytes,
                                                  const int* __restrict__ tgt,
                                                  float* lossG,
                                                  float* gradG) {
  __shared__ unsigned char tg[NN];
  __shared__ float redA[4];
  __shared__ float redB[4];
  const int i = blockIdx.x;
  const int tid = threadIdx.x;
  const size_t rowOff = (size_t)i * NN;

  for (int b = tid * 4; b < NN; b += 1024) {
    int4 t4 = *(const int4*)&tgt[b];
    tg[b + 0] = (unsigned char)t4.x;
    tg[b + 1] = (unsigned char)t4.y;
    tg[b + 2] = (unsigned char)t4.z;
    tg[b + 3] = (unsigned char)t4.w;
  }
  const unsigned char tci = (unsigned char)tgt[i];

  // Load this row's f16 sim (16 KB at the start of grad row i) -> f32 regs.
  float4 sv[8];
#pragma unroll
  for (int q = 0; q < 8; ++q) {
    const f16x4 h = *(const f16x4*)(simBytes + (size_t)i * 32768 +
                                    (size_t)(tid * 4 + q * 1024) * 2);
    sv[q] = make_float4((float)h[0], (float)h[1], (float)h[2], (float)h[3]);
  }
  __syncthreads();

  unsigned mmask = 0;
  float lmin = 1e30f, lmax = -1e30f;
#pragma unroll
  for (int q = 0; q < 8; ++q) {
    uchar4 t4 = *(const uchar4*)&tg[tid * 4 + q * 1024];
    const unsigned char tt[4] = {t4.x, t4.y, t4.z, t4.w};
    const float* sp = (const float*)&sv[q];
#pragma unroll
    for (int e = 0; e < 4; ++e) {
      const bool same = (tt[e] == tci);
      const float s = sp[e];
      if (same) {
        mmask |= (1u << (q * 4 + e));
        if (s < 1.0f) lmin = fminf(lmin, s);
      } else {
        lmax = fmaxf(lmax, s);
      }
    }
  }
#pragma unroll
  for (int off = 32; off > 0; off >>= 1) {
    lmin = fminf(lmin, __shfl_down(lmin, off));
    lmax = fmaxf(lmax, __shfl_down(lmax, off));
  }
  if ((tid & 63) == 0) {
    redA[tid >> 6] = lmin;
    redB[tid >> 6] = lmax;
  }
  __syncthreads();
  const float minpos = fminf(fminf(redA[0], redA[1]), fminf(redA[2], redA[3]));
  const float maxneg = fmaxf(fmaxf(redB[0], redB[1]), fmaxf(redB[2], redB[3]));
  __syncthreads();

  float pc = 0.f, nc = 0.f;
#pragma unroll
  for (int q = 0; q < 8; ++q) {
    const float* sp = (const float*)&sv[q];
#pragma unroll
    for (int e = 0; e < 4; ++e) {
      const bool same = (mmask >> (q * 4 + e)) & 1u;
      const float s = sp[e];
      if (same) {
        if (s < 1.0f && (s - 0.1f) < maxneg) pc += 1.f;
      } else {
        if ((s + 0.1f) > minpos) nc += 1.f;
      }
    }
  }
#pragma unroll
  for (int off = 32; off > 0; off >>= 1) {
    pc += __shfl_down(pc, off);
    nc += __shfl_down(nc, off);
  }
  if ((tid & 63) == 0) {
    redA[tid >> 6] = pc;
    redB[tid >> 6] = nc;
  }
  __syncthreads();
  const float pcnt = redA[0] + redA[1] + redA[2] + redA[3];
  const float ncnt = redB[0] + redB[1] + redB[2] + redB[3];
  const bool valid = (pcnt >= 1.f) && (ncnt >= 1.f);
  const float cp = -2.f / fmaxf(pcnt, 1.f);
  const float cn = 2.f / fmaxf(ncnt, 1.f);

#pragma unroll
  for (int q = 0; q < 8; ++q) {
    const float* sp = (const float*)&sv[q];
    float lo[4], go[4];
#pragma unroll
    for (int e = 0; e < 4; ++e) {
      const float s = sp[e];
      const bool same = (mmask >> (q * 4 + e)) & 1u;
      bool keep = same ? (s < 1.0f && (s - 0.1f) < maxneg)
                       : ((s + 0.1f) > minpos);
      keep = keep && valid;
      const float z = same ? fmaf(-2.f, s, 1.f) : fmaf(40.f, s, -20.f);
      const float ez = __expf(z);
      const float d = 1.f + ez;
      const float ll = __logf(d);
      const float sig = __fdividef(ez, d);
      const float lv = same ? ll : 0.05f * ll;
      const float gv = (same ? cp : cn) * sig;
      lo[e] = keep ? lv : 0.f;
      go[e] = keep ? gv : 0.f;
    }
    const size_t a = rowOff + (size_t)(tid * 4 + q * 1024);
    f32x4 lv4 = {lo[0], lo[1], lo[2], lo[3]};
    f32x4 gv4 = {go[0], go[1], go[2], go[3]};
    __builtin_nontemporal_store(lv4, (f32x4*)&lossG[a]);
    __builtin_nontemporal_store(gv4, (f32x4*)&gradG[a]);
  }
}

extern "C" void kernel_launch(void* const* d_in, const int* in_sizes, int n_in,
                              void* d_out, int out_size, void* d_ws,
                              size_t ws_size, hipStream_t stream) {
  const float* X = (const float*)d_in[0];
  const int* tgt = (const int*)d_in[1];
  float* out = (float*)d_out;
  float* lossG = out;                    // first N*N: pair_loss
  float* gradG = out + (size_t)NN * NN;  // second N*N: pair_grad
  char* simBytes = (char*)gradG;         // f16 sim row i @ grad row i start

  // Xc (4 MiB f16) lives at the start of lossG: read only by sim_mfma, and
  // row_kernel overwrites lossG strictly after sim is fully materialized.
  _Float16* Xc = (_Float16*)lossG;

  hipLaunchKernelGGL(prep_kernel, dim3(NN * DD / (256 * 8)), dim3(256), 0,
                     stream, X, Xc);
  hipLaunchKernelGGL(sim_mfma_kernel, dim3(32 * 64), dim3(512), 0, stream, Xc,
                     simBytes);
  hipLaunchKernelGGL(row_kernel, dim3(NN), dim3(256), 0, stream, simBytes,
                     tgt, lossG, gradG);
}

// Round 18
// 177.290 us; speedup vs baseline: 1.7969x; 1.7969x over previous
//
#include <hip/hip_runtime.h>
#include <hip/hip_fp16.h>

#define NN 8192
#define DD 128

typedef _Float16 f16x8 __attribute__((ext_vector_type(8)));
typedef _Float16 f16x4 __attribute__((ext_vector_type(4)));
typedef float f32x4 __attribute__((ext_vector_type(4)));

// ---------------------------------------------------------------------------
// prep: Xc[row][0..127] = f16(x), Xc[row][128..255] = f16(x - f16(x)).
// sim = Xc @ Xc^T equals x@x^T up to ~1e-6.
// ---------------------------------------------------------------------------
__global__ __launch_bounds__(256) void prep_kernel(const float* __restrict__ X,
                                                   _Float16* __restrict__ Xc) {
  const int t = blockIdx.x * 256 + threadIdx.x;  // 8 elems per thread
  const size_t base = (size_t)t * 8;
  const int row = (int)(base >> 7);
  const int col = (int)(base & 127);
  float4 a = *(const float4*)&X[base];
  float4 b = *(const float4*)&X[base + 4];
  const float av[8] = {a.x, a.y, a.z, a.w, b.x, b.y, b.z, b.w};
  f16x8 h, l;
#pragma unroll
  for (int e = 0; e < 8; ++e) {
    const _Float16 hh = (_Float16)av[e];
    h[e] = hh;
    l[e] = (_Float16)(av[e] - (float)hh);
  }
  *(f16x8*)&Xc[(size_t)row * 256 + col] = h;
  *(f16x8*)&Xc[(size_t)row * 256 + 128 + col] = l;
}

// ---------------------------------------------------------------------------
// sim = Xc @ Xc^T (R16 structure, f16 in-place sim; launch_bounds(512,4) —
// R17 LESSON: per-SIMD VGPR pool = 512 wave-slots (8@64/4@128/2@256, m69);
// 6 waves/EU caps at ~85 VGPRs < our ~150 -> spill; NEVER exceed 4 waves/EU
// with acc[4][4]+frags. 3 blocks/CU is unreachable at this tile.)
// R18 tweak: epilogue phases PAIRED via double-band TrH2 (2 x 64x136 f16 =
// 34 KB <= 48 KB) -> 2 phases instead of 4, halving epilogue barrier drains.
// sim stored as F16 IN-PLACE: sim row i (16 KB) = first half of grad row i;
// row_kernel block i reads exactly what it later overwrites -> hazard-free.
// Geometry: 256x128 tile, 512 thr (8 waves 4x2), wave tile 64x64, BK=32,
// 8 K-steps, double-buffered 24KB buffers = 48 KB LDS -> 2 blocks/CU.
// SYMMETRY ABANDONED (R2,R13). L3 games abandoned (R14,R15).
// DETERMINISM RULE (R9): plain __syncthreads() only.
// Schedule: STAGE(0); sync; { STAGE(ks+1); compute(ks); sync; }
// Swizzle: chunk ^= row&3 on BOTH global source (inverse) and ds_read.
// A/B fragments share the identical k-mapping -> k-permutation cancels.
// C/D layout (m89): col=lane&15, row=(lane>>4)*4+reg.
// Regular (non-NT) sim stores: lines stay L3-resident for row_kernel and are
// overwritten by its NT grad stores before writeback -> most never hit HBM.
// ---------------------------------------------------------------------------
__global__ __launch_bounds__(512, 4) void sim_mfma_kernel(
    const _Float16* __restrict__ Xc, char* __restrict__ simBytes) {
  __shared__ char smem[49152];  // buf b @ b*24576 (A 16KB, B 8KB); TrH2 union

  // bijective XCD swizzle (2048 % 8 == 0)
  const int flat = blockIdx.x;
  const int swz = (flat & 7) * 256 + (flat >> 3);
  const int i0 = (swz >> 6) << 8;  // tile row (32 row-tiles of 256)
  const int j0 = (swz & 63) << 7;  // tile col (64 col-tiles of 128)

  const int tid = threadIdx.x;
  const int lane = tid & 63;
  const int w = tid >> 6;
  const int m = lane & 15, kq = lane >> 4;
  const int wr = w >> 1, wc = w & 1;  // wave rows wr*64+.., cols wc*64+..

  // Staging coords: 3 chunks of 16B per thread per K-step (A 16KB + B 8KB).
  int sg_off[3], sd_off[3], sg_row[3];
#pragma unroll
  for (int it = 0; it < 3; ++it) {
    const int C = it * 512 + tid;
    const int rq = C >> 2;          // row-quad index
    const int k4 = C & 3;
    const int k4p = k4 ^ (rq & 3);  // inverse swizzle on global source
    sg_row[it] = (C < 1024) ? (i0 + rq) : (j0 + rq - 256);
    sg_off[it] = k4p << 4;
    sd_off[it] = C * 16;
  }

#define STAGE(ks, b)                                                         \
  {                                                                          \
    _Pragma("unroll") for (int it = 0; it < 3; ++it) {                       \
      const char* g = (const char*)Xc + ((size_t)sg_row[it] << 9) +          \
                      (ks)*64 + sg_off[it];                                  \
      __builtin_amdgcn_global_load_lds(                                      \
          (const __attribute__((address_space(1))) void*)g,                  \
          (__attribute__((address_space(3))) void*)(smem + (b)*24576 +       \
                                                    sd_off[it]),             \
          16, 0, 0);                                                         \
    }                                                                        \
  }

  f32x4 acc[4][4] = {};

  STAGE(0, 0);
  __syncthreads();  // stage(0) landed (vmcnt 0 + barrier)

#pragma unroll
  for (int ks = 0; ks < 8; ++ks) {
    const int b = ks & 1;
    if (ks < 7) STAGE(ks + 1, b ^ 1);  // prefetch; drained at step-end sync
    const _Float16* As = (const _Float16*)(smem + b * 24576);
    const _Float16* Bs = (const _Float16*)(smem + b * 24576 + 16384);
    f16x8 af[4], bf[4];
#pragma unroll
    for (int f = 0; f < 4; ++f) {
      const int R = wr * 64 + f * 16 + m;  // R&3 == m&3
      af[f] = *(const f16x8*)(As + R * 32 + ((kq ^ (R & 3)) << 3));
    }
#pragma unroll
    for (int g = 0; g < 4; ++g) {
      const int R = wc * 64 + g * 16 + m;
      bf[g] = *(const f16x8*)(Bs + R * 32 + ((kq ^ (R & 3)) << 3));
    }
#pragma unroll
    for (int f = 0; f < 4; ++f)
#pragma unroll
      for (int g = 0; g < 4; ++g)
        acc[f][g] = __builtin_amdgcn_mfma_f32_16x16x32_f16(af[f], bf[g],
                                                           acc[f][g], 0, 0, 0);
    __syncthreads();  // drains vmcnt+lgkm; next-step buffer ready, WAR safe
  }
#undef STAGE

  // Epilogue: 2 paired phases of 128 rows; TrH2 = 2 bands x 64 x 136 f16.
  // Band b of pair p holds global rows i0 + p*128 + b*64 + [0,64).
  _Float16* TrH2 = (_Float16*)smem;  // 2 * 8704 f16 = 34816 B
#pragma unroll
  for (int p = 0; p < 2; ++p) {
    if (p) __syncthreads();
    if ((wr >> 1) == p) {  // 4 waves own this 128-row pair
      const int band = wr & 1;
#pragma unroll
      for (int f = 0; f < 4; ++f)
#pragma unroll
        for (int g = 0; g < 4; ++g)
#pragma unroll
          for (int rg = 0; rg < 4; ++rg)
            TrH2[band * 8704 + (f * 16 + kq * 4 + rg) * 136 +
                 wc * 64 + g * 16 + m] = (_Float16)acc[f][g][rg];
    }
    __syncthreads();
#pragma unroll
    for (int it = 0; it < 4; ++it) {
      const int F = it * 512 + tid;  // [0,2048): 128 rows x 16 chunks
      const int row = F >> 4;        // 0..127
      const int c16 = F & 15;
      const f16x8 v =
          *(const f16x8*)&TrH2[(row >> 6) * 8704 + (row & 63) * 136 + c16 * 8];
      char* dst = simBytes + (size_t)(i0 + p * 128 + row) * 32768 +
                  (size_t)j0 * 2 + c16 * 16;
      *(f16x8*)dst = v;
    }
  }
}

// ---------------------------------------------------------------------------
// row_kernel: one block per row; sim row read as f16 from the first half of
// this block's own grad row (in-place), converted to f32 in registers.
// Native transcendentals, branchless epilogue, non-temporal output stores.
// ---------------------------------------------------------------------------
__global__ __launch_bounds__(256) void row_kernel(const char* simBytes,
                                                  const int* __restrict__ tgt,
                                                  float* lossG,
                                                  float* gradG) {
  __shared__ unsigned char tg[NN];
  __shared__ float redA[4];
  __shared__ float redB[4];
  const int i = blockIdx.x;
  const int tid = threadIdx.x;
  const size_t rowOff = (size_t)i * NN;

  for (int b = tid * 4; b < NN; b += 1024) {
    int4 t4 = *(const int4*)&tgt[b];
    tg[b + 0] = (unsigned char)t4.x;
    tg[b + 1] = (unsigned char)t4.y;
    tg[b + 2] = (unsigned char)t4.z;
    tg[b + 3] = (unsigned char)t4.w;
  }
  const unsigned char tci = (unsigned char)tgt[i];

  // Load this row's f16 sim (16 KB at the start of grad row i) -> f32 regs.
  float4 sv[8];
#pragma unroll
  for (int q = 0; q < 8; ++q) {
    const f16x4 h = *(const f16x4*)(simBytes + (size_t)i * 32768 +
                                    (size_t)(tid * 4 + q * 1024) * 2);
    sv[q] = make_float4((float)h[0], (float)h[1], (float)h[2], (float)h[3]);
  }
  __syncthreads();

  unsigned mmask = 0;
  float lmin = 1e30f, lmax = -1e30f;
#pragma unroll
  for (int q = 0; q < 8; ++q) {
    uchar4 t4 = *(const uchar4*)&tg[tid * 4 + q * 1024];
    const unsigned char tt[4] = {t4.x, t4.y, t4.z, t4.w};
    const float* sp = (const float*)&sv[q];
#pragma unroll
    for (int e = 0; e < 4; ++e) {
      const bool same = (tt[e] == tci);
      const float s = sp[e];
      if (same) {
        mmask |= (1u << (q * 4 + e));
        if (s < 1.0f) lmin = fminf(lmin, s);
      } else {
        lmax = fmaxf(lmax, s);
      }
    }
  }
#pragma unroll
  for (int off = 32; off > 0; off >>= 1) {
    lmin = fminf(lmin, __shfl_down(lmin, off));
    lmax = fmaxf(lmax, __shfl_down(lmax, off));
  }
  if ((tid & 63) == 0) {
    redA[tid >> 6] = lmin;
    redB[tid >> 6] = lmax;
  }
  __syncthreads();
  const float minpos = fminf(fminf(redA[0], redA[1]), fminf(redA[2], redA[3]));
  const float maxneg = fmaxf(fmaxf(redB[0], redB[1]), fmaxf(redB[2], redB[3]));
  __syncthreads();

  float pc = 0.f, nc = 0.f;
#pragma unroll
  for (int q = 0; q < 8; ++q) {
    const float* sp = (const float*)&sv[q];
#pragma unroll
    for (int e = 0; e < 4; ++e) {
      const bool same = (mmask >> (q * 4 + e)) & 1u;
      const float s = sp[e];
      if (same) {
        if (s < 1.0f && (s - 0.1f) < maxneg) pc += 1.f;
      } else {
        if ((s + 0.1f) > minpos) nc += 1.f;
      }
    }
  }
#pragma unroll
  for (int off = 32; off > 0; off >>= 1) {
    pc += __shfl_down(pc, off);
    nc += __shfl_down(nc, off);
  }
  if ((tid & 63) == 0) {
    redA[tid >> 6] = pc;
    redB[tid >> 6] = nc;
  }
  __syncthreads();
  const float pcnt = redA[0] + redA[1] + redA[2] + redA[3];
  const float ncnt = redB[0] + redB[1] + redB[2] + redB[3];
  const bool valid = (pcnt >= 1.f) && (ncnt >= 1.f);
  const float cp = -2.f / fmaxf(pcnt, 1.f);
  const float cn = 2.f / fmaxf(ncnt, 1.f);

#pragma unroll
  for (int q = 0; q < 8; ++q) {
    const float* sp = (const float*)&sv[q];
    float lo[4], go[4];
#pragma unroll
    for (int e = 0; e < 4; ++e) {
      const float s = sp[e];
      const bool same = (mmask >> (q * 4 + e)) & 1u;
      bool keep = same ? (s < 1.0f && (s - 0.1f) < maxneg)
                       : ((s + 0.1f) > minpos);
      keep = keep && valid;
      const float z = same ? fmaf(-2.f, s, 1.f) : fmaf(40.f, s, -20.f);
      const float ez = __expf(z);
      const float d = 1.f + ez;
      const float ll = __logf(d);
      const float sig = __fdividef(ez, d);
      const float lv = same ? ll : 0.05f * ll;
      const float gv = (same ? cp : cn) * sig;
      lo[e] = keep ? lv : 0.f;
      go[e] = keep ? gv : 0.f;
    }
    const size_t a = rowOff + (size_t)(tid * 4 + q * 1024);
    f32x4 lv4 = {lo[0], lo[1], lo[2], lo[3]};
    f32x4 gv4 = {go[0], go[1], go[2], go[3]};
    __builtin_nontemporal_store(lv4, (f32x4*)&lossG[a]);
    __builtin_nontemporal_store(gv4, (f32x4*)&gradG[a]);
  }
}

extern "C" void kernel_launch(void* const* d_in, const int* in_sizes, int n_in,
                              void* d_out, int out_size, void* d_ws,
                              size_t ws_size, hipStream_t stream) {
  const float* X = (const float*)d_in[0];
  const int* tgt = (const int*)d_in[1];
  float* out = (float*)d_out;
  float* lossG = out;                    // first N*N: pair_loss
  float* gradG = out + (size_t)NN * NN;  // second N*N: pair_grad
  char* simBytes = (char*)gradG;         // f16 sim row i @ grad row i start

  // Xc (4 MiB f16) lives at the start of lossG: read only by sim_mfma, and
  // row_kernel overwrites lossG strictly after sim is fully materialized.
  _Float16* Xc = (_Float16*)lossG;

  hipLaunchKernelGGL(prep_kernel, dim3(NN * DD / (256 * 8)), dim3(256), 0,
                     stream, X, Xc);
  hipLaunchKernelGGL(sim_mfma_kernel, dim3(32 * 64), dim3(512), 0, stream, Xc,
                     simBytes);
  hipLaunchKernelGGL(row_kernel, dim3(NN), dim3(256), 0, stream, simBytes,
                     tgt, lossG, gradG);
}